// Round 12
// baseline (168.093 us; speedup 1.0000x reference)
//
#include <hip/hip_runtime.h>

// ---------------- types / helpers ----------------
typedef float  f32x4   __attribute__((ext_vector_type(4)));
typedef float  f32x16  __attribute__((ext_vector_type(16)));
typedef __bf16 bf16x8  __attribute__((ext_vector_type(8)));
typedef __bf16 bf16x2  __attribute__((ext_vector_type(2)));
typedef short  short8v __attribute__((ext_vector_type(8)));
typedef unsigned uint4v __attribute__((ext_vector_type(4)));

__device__ __forceinline__ short f2bf(float f) {
  unsigned u = __float_as_uint(f);
  unsigned r = (u + 0x7FFFu + ((u >> 16) & 1u)) >> 16;  // RNE
  return (short)r;
}

// native v_exp_f32 (exp2) — libm exp2f is a multi-instruction OCML routine
__device__ __forceinline__ float exp2_native(float x) {
#if __has_builtin(__builtin_amdgcn_exp2f)
  return __builtin_amdgcn_exp2f(x);
#else
  float r;
  asm("v_exp_f32 %0, %1" : "=v"(r) : "v"(x));
  return r;
#endif
}

__device__ __forceinline__ f32x4 mfma16(bf16x8 a, bf16x8 b, f32x4 c) {
  return __builtin_amdgcn_mfma_f32_16x16x32_bf16(a, b, c, 0, 0, 0);
}
__device__ __forceinline__ f32x16 mfma32(bf16x8 a, bf16x8 b, f32x16 c) {
  return __builtin_amdgcn_mfma_f32_32x32x16_bf16(a, b, c, 0, 0, 0);
}

// async global->LDS, 16B per lane. lds base must be wave-uniform; HW adds lane*16.
__device__ __forceinline__ void gload16(const void* g, void* l) {
  __builtin_amdgcn_global_load_lds(
      (const __attribute__((address_space(1))) unsigned int*)g,
      (__attribute__((address_space(3))) unsigned int*)l,
      16, 0, 0);
}

// Build PV A-fragment for k-slice pair from packed P dwords via one cross-half
// exchange. pk[i] holds P pairs k_local = 8*(i>>1) + 4*hi + 2*(i&1) + {0,1}.
__device__ __forceinline__ bf16x8 p_exchange(const unsigned* pk, int a, int hi) {
  unsigned y1 = hi ? pk[4 * a + 0] : pk[4 * a + 2];
  unsigned z1 = __shfl_xor(y1, 32);
  unsigned y2 = hi ? pk[4 * a + 1] : pk[4 * a + 3];
  unsigned z2 = __shfl_xor(y2, 32);
  unsigned w0 = hi ? z1 : pk[4 * a + 0];
  unsigned w1 = hi ? z2 : pk[4 * a + 1];
  unsigned w2 = hi ? pk[4 * a + 2] : z1;
  unsigned w3 = hi ? pk[4 * a + 3] : z2;
  uint4v q4 = {w0, w1, w2, w3};
  return __builtin_bit_cast(bf16x8, q4);
}

// ---------------- problem constants ----------------
// B=2, T1=T2=2048, D_MODEL=1024, N_HEAD=16, D_HEAD=64

// ---------------- conversion kernels ----------------
__global__ __launch_bounds__(256) void cvt_copy(const float* __restrict__ in,
                                                short* __restrict__ out, int n4) {
  int i = blockIdx.x * blockDim.x + threadIdx.x;
  int stride = gridDim.x * blockDim.x;
  for (; i < n4; i += stride) {
    float4 v = *(const float4*)&in[i * 4];
    short4 o;
    o.x = f2bf(v.x); o.y = f2bf(v.y); o.z = f2bf(v.z); o.w = f2bf(v.w);
    *(short4*)&out[i * 4] = o;
  }
}

// bias f32 [2048][2048] -> bf16 fragment order frag[Qi][w4][kt][s][half][lane][8]
__global__ __launch_bounds__(256) void cvt_bias_frag(const float* __restrict__ bias,
                                                     short* __restrict__ frag) {
  __shared__ short lb[2][2][64][8];  // [s][half][lane][idx] = 4KB
  int kt = blockIdx.x, w4 = blockIdx.y, Qi = blockIdx.z;
  int t = threadIdx.x;
  int row = t >> 3;                 // 0..31
  int c0 = (t & 7) * 8;             // 0..56
  const float* src = bias + (size_t)(Qi * 128 + w4 * 32 + row) * 2048 + kt * 64 + c0;
  float4 v0 = *(const float4*)(src + 0);
  float4 v1 = *(const float4*)(src + 4);
  float vv[8] = {v0.x, v0.y, v0.z, v0.w, v1.x, v1.y, v1.z, v1.w};
#pragma unroll
  for (int j = 0; j < 8; j++) {
    int kc64 = c0 + j;
    int s = kc64 >> 5, kc5 = kc64 & 31;
    int hi = (kc5 >> 2) & 1, a = kc5 & 3, bq = kc5 >> 3;
    int half = bq >> 1, idx = a + 4 * (bq & 1);
    lb[s][half][hi * 32 + row][idx] = f2bf(vv[j]);
  }
  __syncthreads();
  short8v val = ((const short8v*)&lb[0][0][0][0])[t];
  size_t base = ((size_t)((Qi * 4 + w4) * 32 + kt)) * 2048;  // shorts
  *(short8v*)&frag[base + t * 8] = val;
}

// 4 weight matrices [1024][1024] f32 (row=k,col=n) -> bf16 [n][k], one launch.
__global__ __launch_bounds__(256) void cvt_transpose4(const float* __restrict__ W0,
                                                      const float* __restrict__ W1,
                                                      const float* __restrict__ W2,
                                                      const float* __restrict__ W3,
                                                      short* __restrict__ T0,
                                                      short* __restrict__ T1,
                                                      short* __restrict__ T2,
                                                      short* __restrict__ T3) {
  __shared__ short t_s[64][72];
  int z = blockIdx.z;
  const float* W = (z == 0) ? W0 : (z == 1) ? W1 : (z == 2) ? W2 : W3;
  short* Wt = (z == 0) ? T0 : (z == 1) ? T1 : (z == 2) ? T2 : T3;
  int k0 = blockIdx.y * 64, n0 = blockIdx.x * 64;
  int tid = threadIdx.x;
#pragma unroll
  for (int i = 0; i < 4; i++) {
    int idx = i * 256 + tid;
    int r = idx >> 4, cg = idx & 15;
    float4 v = *(const float4*)&W[(k0 + r) * 1024 + n0 + cg * 4];
    t_s[cg * 4 + 0][r] = f2bf(v.x);
    t_s[cg * 4 + 1][r] = f2bf(v.y);
    t_s[cg * 4 + 2][r] = f2bf(v.z);
    t_s[cg * 4 + 3][r] = f2bf(v.w);
  }
  __syncthreads();
#pragma unroll
  for (int i = 0; i < 2; i++) {
    int idx = i * 256 + tid;
    int r = idx >> 3, cg = idx & 7;
    short8v val = *(short8v*)&t_s[r][cg * 8];
    *(short8v*)&Wt[(n0 + r) * 1024 + k0 + cg * 8] = val;
  }
}

// ---------------- GEMM: C[4096][N] = A[4096][1024] @ Bt^T (r10 config) -------
// EPI 0: N=1024, bf16 scatter to [B,H,T,64]          (Q projection)
// EPI 2: N=1024, f32 out + b_out                      (final projection)
// EPI 3: N=2048, cols<1024 -> K [B,H,T,64]; cols>=1024 -> V^T [B,H,64,T]
template <int EPI>
__global__ __launch_bounds__(256, 4) void gemm_bf16(const short* __restrict__ A,
                                                    const short* __restrict__ Bt,
                                                    void* __restrict__ out,
                                                    void* __restrict__ out2,
                                                    const float* __restrict__ bout) {
  constexpr int KD = 1024;
  constexpr int NB = (EPI == 3) ? 32 : 16;  // N-tiles
  __shared__ short a_s[64][64];
  __shared__ short b_s[64][64];
  int tid = threadIdx.x, w = tid >> 6, lane = tid & 63;
  int g = lane >> 4, c16 = lane & 15;
  int hsw = c16 & 7;

  // XCD swizzle (bijective: grid % 8 == 0)
  int lin = blockIdx.x + NB * blockIdx.y;
  int wk = (lin & 7) * (NB * 8) + (lin >> 3);
  int c0 = (wk & (NB - 1)) * 64, r0 = (wk / NB) * 64;

  int wr = (w >> 1) * 32, wc = (w & 1) * 32;
  f32x4 acc[2][2] = {};

  for (int kt = 0; kt < KD / 64; ++kt) {
    int k0 = kt * 64;
    __syncthreads();
#pragma unroll
    for (int i = 0; i < 2; i++) {
      int cb = i * 256 + w * 64;
      int c = cb + lane;
      int row = c >> 3, kg = c & 7;
      int sw = (kg ^ (row & 7)) * 8;   // pre-swizzled source col
      gload16(A + (r0 + row) * KD + k0 + sw, (char*)a_s + cb * 16);
      gload16(Bt + (c0 + row) * KD + k0 + sw, (char*)b_s + cb * 16);
    }
    __syncthreads();
#pragma unroll
    for (int kk = 0; kk < 2; kk++) {
      bf16x8 af[2], bf[2];
      int sl0 = ((4 * kk + g) ^ hsw) * 8;
#pragma unroll
      for (int m = 0; m < 2; m++) af[m] = *(const bf16x8*)&a_s[wr + m * 16 + c16][sl0];
#pragma unroll
      for (int n = 0; n < 2; n++) bf[n] = *(const bf16x8*)&b_s[wc + n * 16 + c16][sl0];
#pragma unroll
      for (int m = 0; m < 2; m++)
#pragma unroll
        for (int n = 0; n < 2; n++) acc[m][n] = mfma16(af[m], bf[n], acc[m][n]);
    }
  }

#pragma unroll
  for (int m = 0; m < 2; m++)
#pragma unroll
    for (int n = 0; n < 2; n++)
#pragma unroll
      for (int r = 0; r < 4; r++) {
        int row = r0 + wr + m * 16 + g * 4 + r;  // C/D: row=(lane>>4)*4+reg
        int col = c0 + wc + n * 16 + c16;        //      col=lane&15
        float v = acc[m][n][r];
        int b = row >> 11, t = row & 2047;
        if (EPI == 2) {
          ((float*)out)[row * 1024 + col] = v + bout[col];
        } else if (EPI == 0) {
          int h = col >> 6, d = col & 63;
          ((short*)out)[(((b * 16 + h) * 2048) + t) * 64 + d] = f2bf(v);
        } else {  // EPI 3: merged K | V^T
          if (col < 1024) {
            int h = col >> 6, d = col & 63;
            ((short*)out)[(((b * 16 + h) * 2048) + t) * 64 + d] = f2bf(v);
          } else {
            int cv = col - 1024;
            int h = cv >> 6, d = cv & 63;
            ((short*)out2)[(((b * 16 + h) * 64) + d) * 2048 + t] = f2bf(v);
          }
        }
      }
}

// ---------------- flash attention v11 ----------------
// = v10 reordered round (QK0 -> SM0 -> QK1 -> PV0 -> SM1 -> PV1) with:
//  - in-loop compiler fences REMOVED: flash is LDS-bound at 2 blocks/CU, so
//    the VGPR budget is 128/wave; the fences pinned us to 64 and blocked the
//    scheduler from interleaving SM0's VALU/trans with QK1's MFMA / PV0's
//    ds_reads. Let it interleave (peak liveness ~110 < 128 -> no spill).
//  - setprio(1) around MFMA clusters (m191/m218b: pays with phase-split).
__global__ __launch_bounds__(512, 4) void flash_attn(const short* __restrict__ Qg,
                                                     const short* __restrict__ Kg,
                                                     const short* __restrict__ Vtg,
                                                     const short* __restrict__ bfrag,
                                                     short* __restrict__ Og) {
  __shared__ short k_s[2][2][64][64];  // [buf][tile-parity][k][d], swizzled
  __shared__ short v_s[2][2][64][64];  // [buf][tile-parity][d][k], swizzled

  int tid = threadIdx.x, w = tid >> 6, lane = tid & 63;
  int gid = w >> 2, w4 = w & 3;
  int hi = lane >> 5, ll = lane & 31, l7 = ll & 7;

  // head-grouped XCD swizzle: XCD hosts 4 heads x all qb -> K/V L2-fit
  int lin = blockIdx.x + 16 * (blockIdx.y + 16 * blockIdx.z);  // grid (16,16,2)
  int wk = (lin & 7) * 64 + (lin >> 3);
  int Qi = wk & 15;
  int qb = Qi * 128;
  int h = (wk >> 4) & 15;
  int b = wk >> 8;

  const short* Qh = Qg + (size_t)(b * 16 + h) * 2048 * 64;
  const short* Kh = Kg + (size_t)(b * 16 + h) * 2048 * 64;
  const short* Vh = Vtg + (size_t)(b * 16 + h) * 64 * 2048;

  const float C1 = 0.125f * 1.44269504f;                 // atten_scale * log2(e)
  const float C2 = exp2f(-(float)(h + 1)) * 1.44269504f; // head_scale * log2(e)

  int qrow = qb + w4 * 32 + ll;
  const short* bw = bfrag + ((size_t)(Qi * 4 + w4) * 32) * 2048 + lane * 8;

  int srow = tid >> 3, st8 = tid & 7;
  int ssw = (st8 ^ (srow & 7)) * 8;

  // ---- prologue ----
  {
    gload16(Kh + srow * 64 + ssw, (char*)&k_s[0][0][0][0] + w * 64 * 16);
    gload16(Vh + srow * 2048 + ssw, (char*)&v_s[0][0][0][0] + w * 64 * 16);
    gload16(Kh + 64 * 64 + srow * 64 + ssw, (char*)&k_s[0][1][0][0] + w * 64 * 16);
    gload16(Vh + srow * 2048 + 64 + ssw, (char*)&v_s[0][1][0][0] + w * 64 * 16);
  }
  bf16x8 bvA[4];
#pragma unroll
  for (int j = 0; j < 4; j++)
    bvA[j] = *(const bf16x8*)(bw + (size_t)gid * 2048 + j * 512);
  bf16x8 qf[4];
#pragma unroll
  for (int dm = 0; dm < 4; dm++)
    qf[dm] = *(const bf16x8*)(Qh + (size_t)qrow * 64 + dm * 16 + hi * 8);
  asm volatile("" ::: "memory");  // pin prologue VMEM issue order (vmcnt count)

  float l0 = 0.f, l1 = 0.f, l2 = 0.f, l3 = 0.f;
  f32x16 o_acc[2] = {};

  for (int r = 0; r < 16; ++r) {
    int cur = r & 1;
    int kt = 2 * r + gid;

    bf16x8 bvB[4];
    if (r < 15) {
#pragma unroll
      for (int j = 0; j < 4; j++)
        bvB[j] = *(const bf16x8*)(bw + (size_t)(kt + 2) * 2048 + j * 512);
      int tA = 2 * r + 2;
      gload16(Kh + (size_t)tA * 4096 + srow * 64 + ssw,
              (char*)&k_s[cur ^ 1][0][0][0] + w * 64 * 16);
      gload16(Vh + srow * 2048 + tA * 64 + ssw,
              (char*)&v_s[cur ^ 1][0][0][0] + w * 64 * 16);
      gload16(Kh + (size_t)(tA + 1) * 4096 + srow * 64 + ssw,
              (char*)&k_s[cur ^ 1][1][0][0] + w * 64 * 16);
      gload16(Vh + srow * 2048 + (tA + 1) * 64 + ssw,
              (char*)&v_s[cur ^ 1][1][0][0] + w * 64 * 16);
      asm volatile("s_waitcnt vmcnt(8)" ::: "memory");
    } else {
      asm volatile("s_waitcnt vmcnt(0)" ::: "memory");
    }
    __builtin_amdgcn_s_barrier();  // (a) cur buffer staged on all waves

    // ---- QK subtile 0 ----
    f32x16 sacc = {};
    __builtin_amdgcn_s_setprio(1);
#pragma unroll
    for (int dm = 0; dm < 4; dm++) {
      const short* kr = &k_s[cur][gid][ll][((2 * dm + hi) ^ l7) * 8];
      sacc = mfma32(*(const bf16x8*)kr, qf[dm], sacc);
    }
    __builtin_amdgcn_s_setprio(0);

    // ---- SM0 -> pk0 (compiler free to interleave with QK1/PV0 below) ----
    unsigned pk0[8];
#pragma unroll
    for (int i = 0; i < 8; i++) {
      float b0 = (float)(i < 4 ? bvA[0][2 * i] : bvA[1][2 * i - 8]);
      float b1 = (float)(i < 4 ? bvA[0][2 * i + 1] : bvA[1][2 * i - 7]);
      float p0 = exp2_native(sacc[2 * i] * C1 + b0 * C2);
      float p1 = exp2_native(sacc[2 * i + 1] * C1 + b1 * C2);
      l0 += p0; l1 += p1;
      bf16x2 pp = {(__bf16)p0, (__bf16)p1};
      pk0[i] = __builtin_bit_cast(unsigned, pp);
    }

    // ---- QK subtile 1 ----
    f32x16 sacc1 = {};
    __builtin_amdgcn_s_setprio(1);
#pragma unroll
    for (int dm = 0; dm < 4; dm++) {
      const short* kr = &k_s[cur][gid][32 + ll][((2 * dm + hi) ^ l7) * 8];
      sacc1 = mfma32(*(const bf16x8*)kr, qf[dm], sacc1);
    }
    __builtin_amdgcn_s_setprio(0);

    // ---- PV0 ----
    __builtin_amdgcn_s_setprio(1);
#pragma unroll
    for (int a = 0; a < 2; a++) {
      bf16x8 PA = p_exchange(pk0, a, hi);
#pragma unroll
      for (int dt = 0; dt < 2; dt++) {
        const short* vr = &v_s[cur][gid][dt * 32 + ll][((2 * a + hi) ^ l7) * 8];
        o_acc[dt] = mfma32(PA, *(const bf16x8*)vr, o_acc[dt]);
      }
    }
    __builtin_amdgcn_s_setprio(0);

    // ---- SM1 -> pk1 ----
    unsigned pk1[8];
#pragma unroll
    for (int i = 0; i < 8; i++) {
      float b0 = (float)(i < 4 ? bvA[2][2 * i] : bvA[3][2 * i - 8]);
      float b1 = (float)(i < 4 ? bvA[2][2 * i + 1] : bvA[3][2 * i - 7]);
      float p0 = exp2_native(sacc1[2 * i] * C1 + b0 * C2);
      float p1 = exp2_native(sacc1[2 * i + 1] * C1 + b1 * C2);
      l2 += p0; l3 += p1;
      bf16x2 pp = {(__bf16)p0, (__bf16)p1};
      pk1[i] = __builtin_bit_cast(unsigned, pp);
    }

    // ---- PV1 ----
    __builtin_amdgcn_s_setprio(1);
#pragma unroll
    for (int a = 0; a < 2; a++) {
      bf16x8 PA = p_exchange(pk1, a, hi);
#pragma unroll
      for (int dt = 0; dt < 2; dt++) {
        const short* vr = &v_s[cur][gid][dt * 32 + ll][((4 + 2 * a + hi) ^ l7) * 8];
        o_acc[dt] = mfma32(PA, *(const bf16x8*)vr, o_acc[dt]);
      }
    }
    __builtin_amdgcn_s_setprio(0);
    __builtin_amdgcn_s_barrier();  // (b) all waves done reading cur

#pragma unroll
    for (int j = 0; j < 4; j++) bvA[j] = bvB[j];
  }

  float l_run = (l0 + l1) + (l2 + l3);

  // ---- merge the two k-groups: O = (O_e + O_o)/(l_e + l_o) ----
  l_run += __shfl_xor(l_run, 32);
  float* ox = (float*)&k_s[0][0][0][0];  // [4][32][64] f32 = 32 KB (k_s dead)
  float* lx = (float*)&v_s[0][0][0][0];  // [4][32] f32
  if (gid == 1) {
#pragma unroll
    for (int k = 0; k < 32; k++)
      ox[(w4 * 32 + k) * 64 + lane] = o_acc[k >> 4][k & 15];
    if (lane < 32) lx[w4 * 32 + lane] = l_run;
  }
  __syncthreads();
  if (gid == 0) {
    float invl = 1.f / (l_run + lx[w4 * 32 + ll]);
#pragma unroll
    for (int k = 0; k < 32; k++)
      o_acc[k >> 4][k & 15] += ox[(w4 * 32 + k) * 64 + lane];

#pragma unroll
    for (int r = 0; r < 16; r++) {
      int q = (r & 3) + 8 * (r >> 2) + 4 * hi;
      float iv = __shfl(invl, q);
      int tg = qb + w4 * 32 + q;
#pragma unroll
      for (int dt = 0; dt < 2; dt++) {
        Og[(size_t)(b * 2048 + tg) * 1024 + h * 64 + dt * 32 + ll] =
            f2bf(o_acc[dt][r] * iv);
      }
    }
  }
}

// ---------------- launcher ----------------
extern "C" void kernel_launch(void* const* d_in, const int* in_sizes, int n_in,
                              void* d_out, int out_size, void* d_ws, size_t ws_size,
                              hipStream_t stream) {
  const float* x    = (const float*)d_in[0];
  const float* ctx  = (const float*)d_in[1];
  const float* bias = (const float*)d_in[2];
  const float* Wq   = (const float*)d_in[3];
  const float* Wk   = (const float*)d_in[4];
  const float* Wv   = (const float*)d_in[5];
  const float* Wo   = (const float*)d_in[6];
  const float* bo   = (const float*)d_in[7];
  float* out = (float*)d_out;

  char* ws = (char*)d_ws;
  short* x_bf = (short*)(ws + 0);          // 8 MB; reused as bias frag after Q-GEMM
  short* c_bf = (short*)(ws + 8388608);    // 8 MB
  short* wq_t = (short*)(ws + 16777216);   // 2 MB  [N][K]
  short* wk_t = (short*)(ws + 18874368);   // 2 MB  (contiguous with wv_t)
  short* wv_t = (short*)(ws + 20971520);   // 2 MB
  short* wo_t = (short*)(ws + 23068672);   // 2 MB
  short* q_ws = (short*)(ws + 25165824);   // 8 MB  [B,H,T1,64]
  short* k_ws = (short*)(ws + 33554432);   // 8 MB  [B,H,T2,64]
  short* v_ws = (short*)(ws + 41943040);   // 8 MB  [B,H,64,T2]
  short* o_ws = (short*)(ws + 50331648);   // 8 MB  [B,T1,1024]
  short* bias_fr = x_bf;                   // x_bf dead after the Q-GEMM

  cvt_copy<<<1024, 256, 0, stream>>>(x, x_bf, 1048576);
  cvt_copy<<<1024, 256, 0, stream>>>(ctx, c_bf, 1048576);
  dim3 tg(16, 16, 4);
  cvt_transpose4<<<tg, 256, 0, stream>>>(Wq, Wk, Wv, Wo, wq_t, wk_t, wv_t, wo_t);

  dim3 gq(16, 64);  // N=1024
  gemm_bf16<0><<<gq, 256, 0, stream>>>(x_bf, wq_t, q_ws, nullptr, nullptr);
  dim3 gkv(32, 64); // N=2048 merged K|V
  gemm_bf16<3><<<gkv, 256, 0, stream>>>(c_bf, wk_t, k_ws, v_ws, nullptr);

  // bias f32 -> bf16 fragment order (into x_bf region, free after Q-GEMM)
  dim3 bg(32, 4, 16);  // (kt, w4, Qi)
  cvt_bias_frag<<<bg, 256, 0, stream>>>(bias, bias_fr);

  dim3 fg(16, 16, 2);
  flash_attn<<<fg, 512, 0, stream>>>(q_ws, k_ws, v_ws, bias_fr, o_ws);

  dim3 go(16, 64);
  gemm_bf16<2><<<go, 256, 0, stream>>>(o_ws, wo_t, out, nullptr, bo);
}